// Round 9
// baseline (153.241 us; speedup 1.0000x reference)
//
#include <hip/hip_runtime.h>
#include <hip/hip_bf16.h>
#include <math.h>

#define BATCH 8192

typedef __bf16 bf16x8 __attribute__((ext_vector_type(8)));
typedef float f32x4 __attribute__((ext_vector_type(4)));

__device__ __forceinline__ unsigned short f2bf(float f) {
    unsigned int u = __float_as_uint(f);
    u = u + 0x7FFFu + ((u >> 16) & 1u);   // RNE
    return (unsigned short)(u >> 16);
}
__device__ __forceinline__ float bf2f(unsigned short h) {
    return __uint_as_float(((unsigned int)h) << 16);
}
__device__ __forceinline__ void async16(const void* g, void* l) {
    __builtin_amdgcn_global_load_lds(
        (const __attribute__((address_space(1))) unsigned int*)g,
        (__attribute__((address_space(3))) unsigned int*)l, 16, 0, 0);
}

// ---------------------------------------------------------------------------
// Kernel 1: fused prep — weight transposes (blocks 0..2335) + bottom layer 1
// 13->512 (blocks 2336..3359). Independent work, one launch.
// ---------------------------------------------------------------------------
struct TransDesc { const float* W; unsigned short* Wt; int K, N, nkb, tile0; };
struct TransDescs { TransDesc d[6]; };
#define N_TRANS_TILES 2336

__global__ __launch_bounds__(256) void prep_kernel(
    TransDescs td,
    const float* __restrict__ dense,
    const float* __restrict__ W0, const float* __restrict__ b0,
    unsigned short* __restrict__ h1)     // (B,512) bf16
{
    __shared__ float tile[32][33];
    __shared__ float xs[8][16];
    const int t = threadIdx.x;

    if (blockIdx.x < N_TRANS_TILES) {
        const int b = blockIdx.x;
        int i = 0;
        #pragma unroll
        for (int q = 1; q < 6; ++q) if (b >= td.d[q].tile0) i = q;
        const TransDesc D = td.d[i];
        const int tl = b - D.tile0;
        const int kb = (tl % D.nkb) * 32;
        const int nb = (tl / D.nkb) * 32;
        const int Kpad = D.nkb * 32;
        const int tx = t & 31, ty = t >> 5;

        #pragma unroll
        for (int r = 0; r < 32; r += 8) {
            int k = kb + ty + r;
            tile[ty + r][tx] = (k < D.K) ? D.W[(size_t)k * D.N + nb + tx] : 0.f;
        }
        __syncthreads();
        #pragma unroll
        for (int r = 0; r < 32; r += 8) {
            D.Wt[(size_t)(nb + ty + r) * Kpad + kb + tx] = f2bf(tile[tx][ty + r]);
        }
    } else {
        const int row0 = (blockIdx.x - N_TRANS_TILES) * 8;

        if (t < 8 * 13) {
            int r = t / 13, k = t % 13;
            xs[r][k] = dense[(size_t)(row0 + r) * 13 + k];
        }
        __syncthreads();

        #pragma unroll
        for (int jj = 0; jj < 2; ++jj) {
            const int j = t + jj * 256;
            float acc[8];
            const float bj = b0[j];
            #pragma unroll
            for (int r = 0; r < 8; ++r) acc[r] = bj;
            #pragma unroll
            for (int k = 0; k < 13; ++k) {
                float w = W0[k * 512 + j];
                #pragma unroll
                for (int r = 0; r < 8; ++r) acc[r] += xs[r][k] * w;
            }
            #pragma unroll
            for (int r = 0; r < 8; ++r)
                h1[(size_t)(row0 + r) * 512 + j] = f2bf(fmaxf(acc[r], 0.f));
        }
    }
}

// ---------------------------------------------------------------------------
// Kernel 2: embedding gather + pairwise interaction (fp32 dots -> bf16).
// ---------------------------------------------------------------------------
__global__ __launch_bounds__(256) void interact_kernel(
    const int* __restrict__ cat,
    const float* __restrict__ table,
    const float* __restrict__ botf,      // (B,128) fp32
    unsigned short* __restrict__ A0)     // (B,512) bf16
{
    __shared__ float fs[27][132];
    __shared__ int idx[26];

    const int t = threadIdx.x;
    const int row = blockIdx.x;

    if (t < 26) idx[t] = cat[(size_t)row * 26 + t] + t * 100000;
    __syncthreads();

    for (int q = t; q < 27 * 32; q += 256) {
        const int i  = q >> 5;
        const int c4 = q & 31;
        const float* src = (i == 0) ? (botf + (size_t)row * 128)
                                    : (table + (size_t)idx[i - 1] * 128);
        float4 v = reinterpret_cast<const float4*>(src)[c4];
        fs[i][c4 * 4 + 0] = v.x;
        fs[i][c4 * 4 + 1] = v.y;
        fs[i][c4 * 4 + 2] = v.z;
        fs[i][c4 * 4 + 3] = v.w;
    }
    __syncthreads();

    for (int p = t; p < 378; p += 256) {
        int i = 0, rem = p;
        while (rem >= 27 - i) { rem -= 27 - i; ++i; }
        const int j = i + rem;
        float s = 0.f;
        for (int k = 0; k < 128; k += 4) {
            float4 a = *reinterpret_cast<const float4*>(&fs[i][k]);
            float4 b = *reinterpret_cast<const float4*>(&fs[j][k]);
            s += a.x * b.x + a.y * b.y + a.z * b.z + a.w * b.w;
        }
        A0[(size_t)row * 512 + 128 + p] = f2bf(s);
    }
    if (t < 6) A0[(size_t)row * 512 + 506 + t] = 0;  // zero K-pad
}

// ---------------------------------------------------------------------------
// Kernel 3: bf16 MFMA GEMM, 128x128 tile, BK=64, double-buffered with
// COUNTED vmcnt (T4): per iteration {STAGE next (8 loads) -> vmcnt(8) ->
// s_barrier -> ds_read+MFMA -> plain s_barrier}. Next-tile loads stay in
// flight across the barrier; only the current tile's loads are drained.
// 4 waves (2x2), each 64x64 (4x4 frags of 16x16x32, 2 k-sub-steps).
// A:(M,K) bf16, Bt:(N,Kpad) bf16. C = act(A*B+bias) -> bf16 (M,ldc);
// optional fp32 mirror Cf (M,N). XOR-swizzle chunk^=(row&7), pre-swizzled
// global source + swizzled ds_read (rule #21). K % 64 == 0.
// ---------------------------------------------------------------------------
__global__ __launch_bounds__(256) void gemm_bf16_kernel(
    const unsigned short* __restrict__ A,
    const unsigned short* __restrict__ Bt,
    const float* __restrict__ bias,
    unsigned short* __restrict__ C,
    float* __restrict__ Cf,
    int K, int N, int ldc, int relu)
{
    __shared__ unsigned short As[2][128 * 64];
    __shared__ unsigned short Bs[2][128 * 64];

    const int t = threadIdx.x;
    const int lane = t & 63;
    const int wid = t >> 6;
    const int wr = wid >> 1, wc = wid & 1;
    const int row0 = blockIdx.x * 128;
    const int col0 = blockIdx.y * 128;

    // staging roles: q in {0..3}; 16B unit index l16 = q*256+t, 8 chunks/row
    const char* gA[4]; const char* gB[4];
    int ldst[4];
    #pragma unroll
    for (int q = 0; q < 4; ++q) {
        int l16 = q * 256 + t;
        int row = l16 >> 3, chunk = l16 & 7;
        int swz = chunk ^ (row & 7);
        gA[q] = (const char*)A  + ((size_t)(row0 + row) * K + swz * 8) * 2;
        gB[q] = (const char*)Bt + ((size_t)(col0 + row) * K + swz * 8) * 2;
        ldst[q] = l16 * 16;
    }

    // fragment read offsets (bytes), row stride 128 B, phys chunk = c^(r&7)
    const int kb = lane >> 4;
    const int r15 = lane & 15;
    int aoff[4][2], boff[4][2];
    #pragma unroll
    for (int m = 0; m < 4; ++m) {
        int r = wr * 64 + m * 16 + r15;
        int c = wc * 64 + m * 16 + r15;
        #pragma unroll
        for (int ks = 0; ks < 2; ++ks) {
            aoff[m][ks] = r * 128 + (((ks * 4 + kb) ^ (r & 7)) << 4);
            boff[m][ks] = c * 128 + (((ks * 4 + kb) ^ (c & 7)) << 4);
        }
    }

    f32x4 acc[4][4] = {};

    const int nt = K >> 6;

    // prologue: stage tile 0 into buf 0 (8 loads/thread)
    #pragma unroll
    for (int q = 0; q < 4; ++q) {
        async16(gA[q], (char*)As[0] + ldst[q]);
        async16(gB[q], (char*)Bs[0] + ldst[q]);
    }

    int cur = 0;
    // main loop: always has a next tile to stage
    for (int tt = 0; tt < nt - 1; ++tt) {
        const size_t koff = (size_t)(tt + 1) * 128;   // 64 elems * 2 B
        #pragma unroll
        for (int q = 0; q < 4; ++q) {
            async16(gA[q] + koff, (char*)As[cur ^ 1] + ldst[q]);
            async16(gB[q] + koff, (char*)Bs[cur ^ 1] + ldst[q]);
        }
        // wait only the CURRENT tile's 8 loads; next tile's 8 stay in flight
        asm volatile("s_waitcnt vmcnt(8)" ::: "memory");
        __builtin_amdgcn_s_barrier();
        __builtin_amdgcn_sched_barrier(0);

        {
            const char* aB = (const char*)As[cur];
            const char* bB = (const char*)Bs[cur];
            __builtin_amdgcn_s_setprio(1);
            #pragma unroll
            for (int ks = 0; ks < 2; ++ks) {
                bf16x8 af[4], bfr[4];
                #pragma unroll
                for (int m = 0; m < 4; ++m)
                    af[m] = *reinterpret_cast<const bf16x8*>(aB + aoff[m][ks]);
                #pragma unroll
                for (int n = 0; n < 4; ++n)
                    bfr[n] = *reinterpret_cast<const bf16x8*>(bB + boff[n][ks]);

                #pragma unroll
                for (int m = 0; m < 4; ++m)
                    #pragma unroll
                    for (int n = 0; n < 4; ++n)
                        acc[m][n] = __builtin_amdgcn_mfma_f32_16x16x32_bf16(
                            af[m], bfr[n], acc[m][n], 0, 0, 0);
            }
            __builtin_amdgcn_s_setprio(0);
        }
        // plain barrier (no vm drain): reads are retired (MFMA consumed them);
        // buf[cur] may be overwritten only by loads issued after this point.
        __builtin_amdgcn_sched_barrier(0);
        __builtin_amdgcn_s_barrier();
        __builtin_amdgcn_sched_barrier(0);
        cur ^= 1;
    }

    // epilogue tile: drain all remaining staging loads
    asm volatile("s_waitcnt vmcnt(0)" ::: "memory");
    __builtin_amdgcn_s_barrier();
    __builtin_amdgcn_sched_barrier(0);
    {
        const char* aB = (const char*)As[cur];
        const char* bB = (const char*)Bs[cur];
        #pragma unroll
        for (int ks = 0; ks < 2; ++ks) {
            bf16x8 af[4], bfr[4];
            #pragma unroll
            for (int m = 0; m < 4; ++m)
                af[m] = *reinterpret_cast<const bf16x8*>(aB + aoff[m][ks]);
            #pragma unroll
            for (int n = 0; n < 4; ++n)
                bfr[n] = *reinterpret_cast<const bf16x8*>(bB + boff[n][ks]);

            #pragma unroll
            for (int m = 0; m < 4; ++m)
                #pragma unroll
                for (int n = 0; n < 4; ++n)
                    acc[m][n] = __builtin_amdgcn_mfma_f32_16x16x32_bf16(
                        af[m], bfr[n], acc[m][n], 0, 0, 0);
        }
    }

    // C epilogue: within frag, C row = (lane>>4)*4 + reg, col = lane&15
    #pragma unroll
    for (int n = 0; n < 4; ++n) {
        const int col_g = col0 + wc * 64 + n * 16 + r15;
        const float bn = bias[col_g];
        #pragma unroll
        for (int m = 0; m < 4; ++m) {
            const int row_base = row0 + wr * 64 + m * 16 + (lane >> 4) * 4;
            #pragma unroll
            for (int reg = 0; reg < 4; ++reg) {
                float v = acc[m][n][reg] + bn;
                if (relu) v = fmaxf(v, 0.f);
                C[(size_t)(row_base + reg) * ldc + col_g] = f2bf(v);
                if (Cf) Cf[(size_t)(row_base + reg) * N + col_g] = v;
            }
        }
    }
}

// ---------------------------------------------------------------------------
// Kernel 4: final layer 256 -> 1 + sigmoid. One wave per row.
// ---------------------------------------------------------------------------
__global__ __launch_bounds__(256) void final_layer_kernel(
    const unsigned short* __restrict__ A,   // (B,256) bf16
    const float* __restrict__ T4,
    const float* __restrict__ tb4,
    float* __restrict__ out)
{
    const int t = threadIdx.x;
    const int lane = t & 63;
    const int wave = t >> 6;
    const int row = blockIdx.x * 4 + wave;

    ushort4 a4 = reinterpret_cast<const ushort4*>(A + (size_t)row * 256)[lane];
    float4 w = reinterpret_cast<const float4*>(T4)[lane];
    float s = bf2f(a4.x) * w.x + bf2f(a4.y) * w.y + bf2f(a4.z) * w.z + bf2f(a4.w) * w.w;
    #pragma unroll
    for (int off = 32; off > 0; off >>= 1) s += __shfl_down(s, off, 64);
    if (lane == 0) out[row] = 1.f / (1.f + expf(-(s + tb4[0])));
}

// ---------------------------------------------------------------------------
extern "C" void kernel_launch(void* const* d_in, const int* in_sizes, int n_in,
                              void* d_out, int out_size, void* d_ws, size_t ws_size,
                              hipStream_t stream)
{
    const float* dense = (const float*)d_in[0];
    const int*   cat   = (const int*)d_in[1];
    const float* table = (const float*)d_in[2];
    const float* W0 = (const float*)d_in[3];
    const float* b0 = (const float*)d_in[4];
    const float* W1 = (const float*)d_in[5];
    const float* b1 = (const float*)d_in[6];
    const float* W2 = (const float*)d_in[7];
    const float* b2 = (const float*)d_in[8];
    const float* T0 = (const float*)d_in[9];
    const float* tb0 = (const float*)d_in[10];
    const float* T1 = (const float*)d_in[11];
    const float* tb1 = (const float*)d_in[12];
    const float* T2 = (const float*)d_in[13];
    const float* tb2 = (const float*)d_in[14];
    const float* T3 = (const float*)d_in[15];
    const float* tb3 = (const float*)d_in[16];
    const float* T4 = (const float*)d_in[17];
    const float* tb4 = (const float*)d_in[18];
    float* out = (float*)d_out;

    // workspace layout (1 MB units)
    char* ws = (char*)d_ws;
    unsigned short* A0   = (unsigned short*)(ws);                          // 8192x512  bf16  8 MB
    unsigned short* act1 = (unsigned short*)(ws + (((size_t)8)  << 20));   // 8192x1024 bf16 16 MB
    unsigned short* act2 = (unsigned short*)(ws + (((size_t)24) << 20));   // 8192x1024 bf16 16 MB
    float*          botf = (float*)(ws + (((size_t)40) << 20));            // 8192x128  fp32  4 MB
    unsigned short* h1   = (unsigned short*)(ws + (((size_t)44) << 20));   // 8192x512  bf16  8 MB
    unsigned short* h2   = (unsigned short*)(ws + (((size_t)52) << 20));   // 8192x256  bf16  4 MB
    unsigned short* W1t  = (unsigned short*)(ws + (((size_t)56) << 20));   // 256x512
    unsigned short* W2t  = (unsigned short*)(ws + (((size_t)57) << 20));   // 128x256
    unsigned short* T0t  = (unsigned short*)(ws + (((size_t)58) << 20));   // 1024x512
    unsigned short* T1t  = (unsigned short*)(ws + (((size_t)60) << 20));   // 1024x1024
    unsigned short* T2t  = (unsigned short*)(ws + (((size_t)63) << 20));   // 512x1024
    unsigned short* T3t  = (unsigned short*)(ws + (((size_t)66) << 20));   // 256x512

    // fused weight transpose descriptors: {W, Wt, K, N, nkb(=Kpad/32), tile0}
    TransDescs td;
    td.d[0] = { W1, W1t,  512,  256, 16,    0 };   // 16*8  = 128 tiles
    td.d[1] = { W2, W2t,  256,  128,  8,  128 };   // 8*4   = 32
    td.d[2] = { T0, T0t,  506, 1024, 16,  160 };   // 16*32 = 512
    td.d[3] = { T1, T1t, 1024, 1024, 32,  672 };   // 32*32 = 1024
    td.d[4] = { T2, T2t, 1024,  512, 32, 1696 };   // 32*16 = 512
    td.d[5] = { T3, T3t,  512,  256, 16, 2208 };   // 16*8  = 128
    // prep: transposes (2336 blocks) + bottom layer 1 (1024 blocks)
    hipLaunchKernelGGL(prep_kernel, dim3(N_TRANS_TILES + BATCH / 8), dim3(256), 0, stream,
                       td, dense, W0, b0, h1);

    // bottom layer 2: (B,512)@(512,256) -> h2, relu
    hipLaunchKernelGGL(gemm_bf16_kernel, dim3(BATCH / 128, 256 / 128), dim3(256), 0, stream,
                       h1, W1t, b1, h2, (float*)nullptr, 512, 256, 256, 1);

    // bottom layer 3: (B,256)@(256,128) -> A0[:,0:128] (ldc=512) + botf fp32
    hipLaunchKernelGGL(gemm_bf16_kernel, dim3(BATCH / 128, 1), dim3(256), 0, stream,
                       h2, W2t, b2, A0, botf, 256, 128, 512, 1);

    // gather + interaction -> A0[:,128:506], zero pad
    hipLaunchKernelGGL(interact_kernel, dim3(BATCH), dim3(256), 0, stream,
                       cat, table, botf, A0);

    // top MLP (bf16 MFMA)
    hipLaunchKernelGGL(gemm_bf16_kernel, dim3(BATCH / 128, 1024 / 128), dim3(256), 0, stream,
                       A0, T0t, tb0, act1, (float*)nullptr, 512, 1024, 1024, 1);
    hipLaunchKernelGGL(gemm_bf16_kernel, dim3(BATCH / 128, 1024 / 128), dim3(256), 0, stream,
                       act1, T1t, tb1, act2, (float*)nullptr, 1024, 1024, 1024, 1);
    hipLaunchKernelGGL(gemm_bf16_kernel, dim3(BATCH / 128, 512 / 128), dim3(256), 0, stream,
                       act2, T2t, tb2, act1, (float*)nullptr, 1024, 512, 512, 1);
    hipLaunchKernelGGL(gemm_bf16_kernel, dim3(BATCH / 128, 256 / 128), dim3(256), 0, stream,
                       act1, T3t, tb3, act2, (float*)nullptr, 512, 256, 256, 1);

    // final layer
    hipLaunchKernelGGL(final_layer_kernel, dim3(BATCH / 4), dim3(256), 0, stream,
                       act2, T4, tb4, out);
}

// Round 10
// 135.929 us; speedup vs baseline: 1.1274x; 1.1274x over previous
//
#include <hip/hip_runtime.h>
#include <hip/hip_bf16.h>
#include <math.h>

#define BATCH 8192

typedef __bf16 bf16x8 __attribute__((ext_vector_type(8)));
typedef float f32x4 __attribute__((ext_vector_type(4)));

__device__ __forceinline__ unsigned short f2bf(float f) {
    unsigned int u = __float_as_uint(f);
    u = u + 0x7FFFu + ((u >> 16) & 1u);   // RNE
    return (unsigned short)(u >> 16);
}
__device__ __forceinline__ float bf2f(unsigned short h) {
    return __uint_as_float(((unsigned int)h) << 16);
}
__device__ __forceinline__ void async16(const void* g, void* l) {
    __builtin_amdgcn_global_load_lds(
        (const __attribute__((address_space(1))) unsigned int*)g,
        (__attribute__((address_space(3))) unsigned int*)l, 16, 0, 0);
}

// ---------------------------------------------------------------------------
// Kernel 1: fused prep — weight transposes (blocks 0..2335) + bottom layer 1
// 13->512 (blocks 2336..3359).
// ---------------------------------------------------------------------------
struct TransDesc { const float* W; unsigned short* Wt; int K, N, nkb, tile0; };
struct TransDescs { TransDesc d[6]; };
#define N_TRANS_TILES 2336

__global__ __launch_bounds__(256) void prep_kernel(
    TransDescs td,
    const float* __restrict__ dense,
    const float* __restrict__ W0, const float* __restrict__ b0,
    unsigned short* __restrict__ h1)     // (B,512) bf16
{
    __shared__ float tile[32][33];
    __shared__ float xs[8][16];
    const int t = threadIdx.x;

    if (blockIdx.x < N_TRANS_TILES) {
        const int b = blockIdx.x;
        int i = 0;
        #pragma unroll
        for (int q = 1; q < 6; ++q) if (b >= td.d[q].tile0) i = q;
        const TransDesc D = td.d[i];
        const int tl = b - D.tile0;
        const int kb = (tl % D.nkb) * 32;
        const int nb = (tl / D.nkb) * 32;
        const int Kpad = D.nkb * 32;
        const int tx = t & 31, ty = t >> 5;

        #pragma unroll
        for (int r = 0; r < 32; r += 8) {
            int k = kb + ty + r;
            tile[ty + r][tx] = (k < D.K) ? D.W[(size_t)k * D.N + nb + tx] : 0.f;
        }
        __syncthreads();
        #pragma unroll
        for (int r = 0; r < 32; r += 8) {
            D.Wt[(size_t)(nb + ty + r) * Kpad + kb + tx] = f2bf(tile[tx][ty + r]);
        }
    } else {
        const int row0 = (blockIdx.x - N_TRANS_TILES) * 8;

        if (t < 8 * 13) {
            int r = t / 13, k = t % 13;
            xs[r][k] = dense[(size_t)(row0 + r) * 13 + k];
        }
        __syncthreads();

        #pragma unroll
        for (int jj = 0; jj < 2; ++jj) {
            const int j = t + jj * 256;
            float acc[8];
            const float bj = b0[j];
            #pragma unroll
            for (int r = 0; r < 8; ++r) acc[r] = bj;
            #pragma unroll
            for (int k = 0; k < 13; ++k) {
                float w = W0[k * 512 + j];
                #pragma unroll
                for (int r = 0; r < 8; ++r) acc[r] += xs[r][k] * w;
            }
            #pragma unroll
            for (int r = 0; r < 8; ++r)
                h1[(size_t)(row0 + r) * 512 + j] = f2bf(fmaxf(acc[r], 0.f));
        }
    }
}

// ---------------------------------------------------------------------------
// Kernel 2: embedding gather + pairwise interaction. bot_out read as bf16
// from A0[:,0:128]; embeddings fp32. fp32 dots -> bf16 into A0[:,128:506].
// ---------------------------------------------------------------------------
__global__ __launch_bounds__(256) void interact_kernel(
    const int* __restrict__ cat,
    const float* __restrict__ table,
    unsigned short* __restrict__ A0)     // (B,512) bf16
{
    __shared__ float fs[27][132];
    __shared__ int idx[26];

    const int t = threadIdx.x;
    const int row = blockIdx.x;

    if (t < 26) idx[t] = cat[(size_t)row * 26 + t] + t * 100000;
    __syncthreads();

    // feature 0: bot_out bf16 from A0
    if (t < 32) {
        ushort4 u = reinterpret_cast<const ushort4*>(A0 + (size_t)row * 512)[t];
        fs[0][t * 4 + 0] = bf2f(u.x);
        fs[0][t * 4 + 1] = bf2f(u.y);
        fs[0][t * 4 + 2] = bf2f(u.z);
        fs[0][t * 4 + 3] = bf2f(u.w);
    }
    // features 1..26: embedding rows fp32 (26*32 = 832 float4 units)
    for (int q = t; q < 26 * 32; q += 256) {
        const int i  = (q >> 5) + 1;
        const int c4 = q & 31;
        float4 v = reinterpret_cast<const float4*>(table + (size_t)idx[i - 1] * 128)[c4];
        fs[i][c4 * 4 + 0] = v.x;
        fs[i][c4 * 4 + 1] = v.y;
        fs[i][c4 * 4 + 2] = v.z;
        fs[i][c4 * 4 + 3] = v.w;
    }
    __syncthreads();

    for (int p = t; p < 378; p += 256) {
        int i = 0, rem = p;
        while (rem >= 27 - i) { rem -= 27 - i; ++i; }
        const int j = i + rem;
        float s = 0.f;
        for (int k = 0; k < 128; k += 4) {
            float4 a = *reinterpret_cast<const float4*>(&fs[i][k]);
            float4 b = *reinterpret_cast<const float4*>(&fs[j][k]);
            s += a.x * b.x + a.y * b.y + a.z * b.z + a.w * b.w;
        }
        A0[(size_t)row * 512 + 128 + p] = f2bf(s);
    }
    if (t < 6) A0[(size_t)row * 512 + 506 + t] = 0;  // zero K-pad
}

// ---------------------------------------------------------------------------
// Kernel 3: bf16 MFMA GEMM, 128xBN tile (BN = 128 or 64), BK=64,
// double-buffered (stage t+1 || compute t, one __syncthreads per K-tile).
// 4 waves (2x2): wave tile 64 x BN/2, 4 x BN/32 frags of 16x16x32.
// A:(M,K) bf16, Bt:(N,Kpad) bf16. C = act(A*B+bias) -> bf16 (M,ldc).
// XOR-swizzle chunk^=(row&7), pre-swizzled source + swizzled read. K%64==0.
// ---------------------------------------------------------------------------
template<int BN>
__global__ __launch_bounds__(256) void gemm_bf16_kernel(
    const unsigned short* __restrict__ A,
    const unsigned short* __restrict__ Bt,
    const float* __restrict__ bias,
    unsigned short* __restrict__ C,
    int K, int ldc, int relu)
{
    constexpr int NF = BN / 32;  // n-frags per wave == B stage units/thread
    __shared__ unsigned short As[2][128 * 64];
    __shared__ unsigned short Bs[2][BN * 64];

    const int t = threadIdx.x;
    const int lane = t & 63;
    const int wid = t >> 6;
    const int wr = wid >> 1, wc = wid & 1;
    const int row0 = blockIdx.x * 128;
    const int col0 = blockIdx.y * BN;

    // A staging: 4 units/thread; B staging: NF units/thread (8 chunks/row)
    const char* gA[4]; int ldstA[4];
    #pragma unroll
    for (int q = 0; q < 4; ++q) {
        int l16 = q * 256 + t;
        int row = l16 >> 3, chunk = l16 & 7;
        int swz = chunk ^ (row & 7);
        gA[q] = (const char*)A + ((size_t)(row0 + row) * K + swz * 8) * 2;
        ldstA[q] = l16 * 16;
    }
    const char* gB[NF]; int ldstB[NF];
    #pragma unroll
    for (int q = 0; q < NF; ++q) {
        int l16 = q * 256 + t;
        int row = l16 >> 3, chunk = l16 & 7;
        int swz = chunk ^ (row & 7);
        gB[q] = (const char*)Bt + ((size_t)(col0 + row) * K + swz * 8) * 2;
        ldstB[q] = l16 * 16;
    }

    // fragment read offsets (bytes), row stride 128 B, phys chunk = c^(r&7)
    const int kb = lane >> 4;
    const int r15 = lane & 15;
    int aoff[4][2], boff[NF][2];
    #pragma unroll
    for (int m = 0; m < 4; ++m) {
        int r = wr * 64 + m * 16 + r15;
        #pragma unroll
        for (int ks = 0; ks < 2; ++ks)
            aoff[m][ks] = r * 128 + (((ks * 4 + kb) ^ (r & 7)) << 4);
    }
    #pragma unroll
    for (int n = 0; n < NF; ++n) {
        int c = wc * (BN / 2) + n * 16 + r15;
        #pragma unroll
        for (int ks = 0; ks < 2; ++ks)
            boff[n][ks] = c * 128 + (((ks * 4 + kb) ^ (c & 7)) << 4);
    }

    f32x4 acc[4][NF] = {};

    const int nt = K >> 6;

    // prologue: stage tile 0 into buf 0
    #pragma unroll
    for (int q = 0; q < 4; ++q)  async16(gA[q], (char*)As[0] + ldstA[q]);
    #pragma unroll
    for (int q = 0; q < NF; ++q) async16(gB[q], (char*)Bs[0] + ldstB[q]);
    __syncthreads();

    int cur = 0;
    for (int tt = 0; tt < nt; ++tt) {
        if (tt + 1 < nt) {
            const size_t koff = (size_t)(tt + 1) * 128;   // 64 elems * 2 B
            #pragma unroll
            for (int q = 0; q < 4; ++q)
                async16(gA[q] + koff, (char*)As[cur ^ 1] + ldstA[q]);
            #pragma unroll
            for (int q = 0; q < NF; ++q)
                async16(gB[q] + koff, (char*)Bs[cur ^ 1] + ldstB[q]);
        }

        const char* aB = (const char*)As[cur];
        const char* bB = (const char*)Bs[cur];
        #pragma unroll
        for (int ks = 0; ks < 2; ++ks) {
            bf16x8 af[4], bfr[NF];
            #pragma unroll
            for (int m = 0; m < 4; ++m)
                af[m] = *reinterpret_cast<const bf16x8*>(aB + aoff[m][ks]);
            #pragma unroll
            for (int n = 0; n < NF; ++n)
                bfr[n] = *reinterpret_cast<const bf16x8*>(bB + boff[n][ks]);

            #pragma unroll
            for (int m = 0; m < 4; ++m)
                #pragma unroll
                for (int n = 0; n < NF; ++n)
                    acc[m][n] = __builtin_amdgcn_mfma_f32_16x16x32_bf16(
                        af[m], bfr[n], acc[m][n], 0, 0, 0);
        }
        __syncthreads();
        cur ^= 1;
    }

    // epilogue: within frag, C row = (lane>>4)*4 + reg, col = lane&15
    #pragma unroll
    for (int n = 0; n < NF; ++n) {
        const int col_g = col0 + wc * (BN / 2) + n * 16 + r15;
        const float bn = bias[col_g];
        #pragma unroll
        for (int m = 0; m < 4; ++m) {
            const int row_base = row0 + wr * 64 + m * 16 + (lane >> 4) * 4;
            #pragma unroll
            for (int reg = 0; reg < 4; ++reg) {
                float v = acc[m][n][reg] + bn;
                if (relu) v = fmaxf(v, 0.f);
                C[(size_t)(row_base + reg) * ldc + col_g] = f2bf(v);
            }
        }
    }
}

// ---------------------------------------------------------------------------
// Kernel 4: final layer 256 -> 1 + sigmoid. One wave per row.
// ---------------------------------------------------------------------------
__global__ __launch_bounds__(256) void final_layer_kernel(
    const unsigned short* __restrict__ A,   // (B,256) bf16
    const float* __restrict__ T4,
    const float* __restrict__ tb4,
    float* __restrict__ out)
{
    const int t = threadIdx.x;
    const int lane = t & 63;
    const int wave = t >> 6;
    const int row = blockIdx.x * 4 + wave;

    ushort4 a4 = reinterpret_cast<const ushort4*>(A + (size_t)row * 256)[lane];
    float4 w = reinterpret_cast<const float4*>(T4)[lane];
    float s = bf2f(a4.x) * w.x + bf2f(a4.y) * w.y + bf2f(a4.z) * w.z + bf2f(a4.w) * w.w;
    #pragma unroll
    for (int off = 32; off > 0; off >>= 1) s += __shfl_down(s, off, 64);
    if (lane == 0) out[row] = 1.f / (1.f + expf(-(s + tb4[0])));
}

// ---------------------------------------------------------------------------
extern "C" void kernel_launch(void* const* d_in, const int* in_sizes, int n_in,
                              void* d_out, int out_size, void* d_ws, size_t ws_size,
                              hipStream_t stream)
{
    const float* dense = (const float*)d_in[0];
    const int*   cat   = (const int*)d_in[1];
    const float* table = (const float*)d_in[2];
    const float* W0 = (const float*)d_in[3];
    const float* b0 = (const float*)d_in[4];
    const float* W1 = (const float*)d_in[5];
    const float* b1 = (const float*)d_in[6];
    const float* W2 = (const float*)d_in[7];
    const float* b2 = (const float*)d_in[8];
    const float* T0 = (const float*)d_in[9];
    const float* tb0 = (const float*)d_in[10];
    const float* T1 = (const float*)d_in[11];
    const float* tb1 = (const float*)d_in[12];
    const float* T2 = (const float*)d_in[13];
    const float* tb2 = (const float*)d_in[14];
    const float* T3 = (const float*)d_in[15];
    const float* tb3 = (const float*)d_in[16];
    const float* T4 = (const float*)d_in[17];
    const float* tb4 = (const float*)d_in[18];
    float* out = (float*)d_out;

    // workspace layout (1 MB units)
    char* ws = (char*)d_ws;
    unsigned short* A0   = (unsigned short*)(ws);                          // 8192x512  bf16  8 MB
    unsigned short* act1 = (unsigned short*)(ws + (((size_t)8)  << 20));   // 8192x1024 bf16 16 MB
    unsigned short* act2 = (unsigned short*)(ws + (((size_t)24) << 20));   // 8192x1024 bf16 16 MB
    unsigned short* h1   = (unsigned short*)(ws + (((size_t)44) << 20));   // 8192x512  bf16  8 MB
    unsigned short* h2   = (unsigned short*)(ws + (((size_t)52) << 20));   // 8192x256  bf16  4 MB
    unsigned short* W1t  = (unsigned short*)(ws + (((size_t)56) << 20));   // 256x512
    unsigned short* W2t  = (unsigned short*)(ws + (((size_t)57) << 20));   // 128x256
    unsigned short* T0t  = (unsigned short*)(ws + (((size_t)58) << 20));   // 1024x512
    unsigned short* T1t  = (unsigned short*)(ws + (((size_t)60) << 20));   // 1024x1024
    unsigned short* T2t  = (unsigned short*)(ws + (((size_t)63) << 20));   // 512x1024
    unsigned short* T3t  = (unsigned short*)(ws + (((size_t)66) << 20));   // 256x512

    // fused weight transpose descriptors: {W, Wt, K, N, nkb(=Kpad/32), tile0}
    TransDescs td;
    td.d[0] = { W1, W1t,  512,  256, 16,    0 };   // 16*8  = 128 tiles
    td.d[1] = { W2, W2t,  256,  128,  8,  128 };   // 8*4   = 32
    td.d[2] = { T0, T0t,  506, 1024, 16,  160 };   // 16*32 = 512
    td.d[3] = { T1, T1t, 1024, 1024, 32,  672 };   // 32*32 = 1024
    td.d[4] = { T2, T2t, 1024,  512, 32, 1696 };   // 32*16 = 512
    td.d[5] = { T3, T3t,  512,  256, 16, 2208 };   // 16*8  = 128
    // prep: transposes (2336 blocks) + bottom layer 1 (1024 blocks)
    hipLaunchKernelGGL(prep_kernel, dim3(N_TRANS_TILES + BATCH / 8), dim3(256), 0, stream,
                       td, dense, W0, b0, h1);

    // bottom layer 2: (B,512)@(512,256) -> h2, relu  [BN=64: 256 blocks]
    hipLaunchKernelGGL((gemm_bf16_kernel<64>), dim3(BATCH / 128, 256 / 64), dim3(256), 0, stream,
                       h1, W1t, b1, h2, 512, 256, 1);

    // bottom layer 3: (B,256)@(256,128) -> A0[:,0:128] (ldc=512)  [BN=64: 128 blocks]
    hipLaunchKernelGGL((gemm_bf16_kernel<64>), dim3(BATCH / 128, 128 / 64), dim3(256), 0, stream,
                       h2, W2t, b2, A0, 256, 512, 1);

    // gather + interaction -> A0[:,128:506], zero pad
    hipLaunchKernelGGL(interact_kernel, dim3(BATCH), dim3(256), 0, stream,
                       cat, table, A0);

    // top MLP (bf16 MFMA)
    hipLaunchKernelGGL((gemm_bf16_kernel<128>), dim3(BATCH / 128, 1024 / 128), dim3(256), 0, stream,
                       A0, T0t, tb0, act1, 512, 1024, 1);
    hipLaunchKernelGGL((gemm_bf16_kernel<128>), dim3(BATCH / 128, 1024 / 128), dim3(256), 0, stream,
                       act1, T1t, tb1, act2, 1024, 1024, 1);
    hipLaunchKernelGGL((gemm_bf16_kernel<128>), dim3(BATCH / 128, 512 / 128), dim3(256), 0, stream,
                       act2, T2t, tb2, act1, 1024, 512, 1);
    hipLaunchKernelGGL((gemm_bf16_kernel<64>), dim3(BATCH / 128, 256 / 64), dim3(256), 0, stream,
                       act1, T3t, tb3, act2, 512, 256, 1);

    // final layer
    hipLaunchKernelGGL(final_layer_kernel, dim3(BATCH / 4), dim3(256), 0, stream,
                       act2, T4, tb4, out);
}

// Round 11
// 135.465 us; speedup vs baseline: 1.1312x; 1.0034x over previous
//
#include <hip/hip_runtime.h>
#include <hip/hip_bf16.h>
#include <math.h>

#define BATCH 8192

typedef __bf16 bf16x8 __attribute__((ext_vector_type(8)));
typedef float f32x4 __attribute__((ext_vector_type(4)));
typedef float f32x16 __attribute__((ext_vector_type(16)));

__device__ __forceinline__ unsigned short f2bf(float f) {
    unsigned int u = __float_as_uint(f);
    u = u + 0x7FFFu + ((u >> 16) & 1u);   // RNE
    return (unsigned short)(u >> 16);
}
__device__ __forceinline__ float bf2f(unsigned short h) {
    return __uint_as_float(((unsigned int)h) << 16);
}
__device__ __forceinline__ void async16(const void* g, void* l) {
    __builtin_amdgcn_global_load_lds(
        (const __attribute__((address_space(1))) unsigned int*)g,
        (__attribute__((address_space(3))) unsigned int*)l, 16, 0, 0);
}

// ---------------------------------------------------------------------------
// Kernel 1: fused prep — weight transposes (blocks 0..2335) + bottom layer 1
// 13->512 (blocks 2336..3359).
// ---------------------------------------------------------------------------
struct TransDesc { const float* W; unsigned short* Wt; int K, N, nkb, tile0; };
struct TransDescs { TransDesc d[6]; };
#define N_TRANS_TILES 2336

__global__ __launch_bounds__(256) void prep_kernel(
    TransDescs td,
    const float* __restrict__ dense,
    const float* __restrict__ W0, const float* __restrict__ b0,
    unsigned short* __restrict__ h1)     // (B,512) bf16
{
    __shared__ float tile[32][33];
    __shared__ float xs[8][16];
    const int t = threadIdx.x;

    if (blockIdx.x < N_TRANS_TILES) {
        const int b = blockIdx.x;
        int i = 0;
        #pragma unroll
        for (int q = 1; q < 6; ++q) if (b >= td.d[q].tile0) i = q;
        const TransDesc D = td.d[i];
        const int tl = b - D.tile0;
        const int kb = (tl % D.nkb) * 32;
        const int nb = (tl / D.nkb) * 32;
        const int Kpad = D.nkb * 32;
        const int tx = t & 31, ty = t >> 5;

        #pragma unroll
        for (int r = 0; r < 32; r += 8) {
            int k = kb + ty + r;
            tile[ty + r][tx] = (k < D.K) ? D.W[(size_t)k * D.N + nb + tx] : 0.f;
        }
        __syncthreads();
        #pragma unroll
        for (int r = 0; r < 32; r += 8) {
            D.Wt[(size_t)(nb + ty + r) * Kpad + kb + tx] = f2bf(tile[tx][ty + r]);
        }
    } else {
        const int row0 = (blockIdx.x - N_TRANS_TILES) * 8;

        if (t < 8 * 13) {
            int r = t / 13, k = t % 13;
            xs[r][k] = dense[(size_t)(row0 + r) * 13 + k];
        }
        __syncthreads();

        #pragma unroll
        for (int jj = 0; jj < 2; ++jj) {
            const int j = t + jj * 256;
            float acc[8];
            const float bj = b0[j];
            #pragma unroll
            for (int r = 0; r < 8; ++r) acc[r] = bj;
            #pragma unroll
            for (int k = 0; k < 13; ++k) {
                float w = W0[k * 512 + j];
                #pragma unroll
                for (int r = 0; r < 8; ++r) acc[r] += xs[r][k] * w;
            }
            #pragma unroll
            for (int r = 0; r < 8; ++r)
                h1[(size_t)(row0 + r) * 512 + j] = f2bf(fmaxf(acc[r], 0.f));
        }
    }
}

// ---------------------------------------------------------------------------
// Kernel 2: embedding gather + pairwise interaction. bot_out read as bf16
// from A0[:,0:128]; embeddings fp32. fp32 dots -> bf16 into A0[:,128:506].
// ---------------------------------------------------------------------------
__global__ __launch_bounds__(256) void interact_kernel(
    const int* __restrict__ cat,
    const float* __restrict__ table,
    unsigned short* __restrict__ A0)     // (B,512) bf16
{
    __shared__ float fs[27][132];
    __shared__ int idx[26];

    const int t = threadIdx.x;
    const int row = blockIdx.x;

    if (t < 26) idx[t] = cat[(size_t)row * 26 + t] + t * 100000;
    __syncthreads();

    // feature 0: bot_out bf16 from A0
    if (t < 32) {
        ushort4 u = reinterpret_cast<const ushort4*>(A0 + (size_t)row * 512)[t];
        fs[0][t * 4 + 0] = bf2f(u.x);
        fs[0][t * 4 + 1] = bf2f(u.y);
        fs[0][t * 4 + 2] = bf2f(u.z);
        fs[0][t * 4 + 3] = bf2f(u.w);
    }
    // features 1..26: embedding rows fp32 (26*32 = 832 float4 units)
    for (int q = t; q < 26 * 32; q += 256) {
        const int i  = (q >> 5) + 1;
        const int c4 = q & 31;
        float4 v = reinterpret_cast<const float4*>(table + (size_t)idx[i - 1] * 128)[c4];
        fs[i][c4 * 4 + 0] = v.x;
        fs[i][c4 * 4 + 1] = v.y;
        fs[i][c4 * 4 + 2] = v.z;
        fs[i][c4 * 4 + 3] = v.w;
    }
    __syncthreads();

    for (int p = t; p < 378; p += 256) {
        int i = 0, rem = p;
        while (rem >= 27 - i) { rem -= 27 - i; ++i; }
        const int j = i + rem;
        float s = 0.f;
        for (int k = 0; k < 128; k += 4) {
            float4 a = *reinterpret_cast<const float4*>(&fs[i][k]);
            float4 b = *reinterpret_cast<const float4*>(&fs[j][k]);
            s += a.x * b.x + a.y * b.y + a.z * b.z + a.w * b.w;
        }
        A0[(size_t)row * 512 + 128 + p] = f2bf(s);
    }
    if (t < 6) A0[(size_t)row * 512 + 506 + t] = 0;  // zero K-pad
}

// ---------------------------------------------------------------------------
// Kernel 3: bf16 MFMA GEMM, 128xBN tile (BN = 128 or 64), BK=64,
// double-buffered (stage t+1 || compute t, one __syncthreads per K-tile).
// 4 waves (2x2): wave tile 64 x BN/2 using 32x32x16 MFMA:
//   m-frags = 2 (64/32), n-frags = BN/64, 4 k-sub-steps of 16.
// A:(M,K) bf16, Bt:(N,Kpad) bf16. C = act(A*B+bias) -> bf16 (M,ldc).
// XOR-swizzle chunk^=(row&7), pre-swizzled source + swizzled read. K%64==0.
// A/B frag: lane holds row=lane&31, k=(lane>>5)*8..+8 (16B = chunk ks*2+(lane>>5)).
// C/D frag (m74/m101): col=lane&31, row=(reg&3)+8*(reg>>2)+4*(lane>>5).
// ---------------------------------------------------------------------------
template<int BN>
__global__ __launch_bounds__(256) void gemm_bf16_kernel(
    const unsigned short* __restrict__ A,
    const unsigned short* __restrict__ Bt,
    const float* __restrict__ bias,
    unsigned short* __restrict__ C,
    int K, int ldc, int relu)
{
    constexpr int NST = BN / 32;   // B staging 16B-units per thread
    constexpr int NFR = BN / 64;   // 32x32 n-frags per wave
    __shared__ unsigned short As[2][128 * 64];
    __shared__ unsigned short Bs[2][BN * 64];

    const int t = threadIdx.x;
    const int lane = t & 63;
    const int wid = t >> 6;
    const int wr = wid >> 1, wc = wid & 1;
    const int row0 = blockIdx.x * 128;
    const int col0 = blockIdx.y * BN;

    // A staging: 4 units/thread; B staging: NST units/thread (8 chunks/row)
    const char* gA[4]; int ldstA[4];
    #pragma unroll
    for (int q = 0; q < 4; ++q) {
        int l16 = q * 256 + t;
        int row = l16 >> 3, chunk = l16 & 7;
        int swz = chunk ^ (row & 7);
        gA[q] = (const char*)A + ((size_t)(row0 + row) * K + swz * 8) * 2;
        ldstA[q] = l16 * 16;
    }
    const char* gB[NST]; int ldstB[NST];
    #pragma unroll
    for (int q = 0; q < NST; ++q) {
        int l16 = q * 256 + t;
        int row = l16 >> 3, chunk = l16 & 7;
        int swz = chunk ^ (row & 7);
        gB[q] = (const char*)Bt + ((size_t)(col0 + row) * K + swz * 8) * 2;
        ldstB[q] = l16 * 16;
    }

    // fragment read offsets (bytes), row stride 128 B, phys chunk = c^(r&7)
    const int r31 = lane & 31;
    const int kb2 = lane >> 5;   // 0..1
    int aoff[2][4], boff[NFR][4];
    #pragma unroll
    for (int m = 0; m < 2; ++m) {
        int r = wr * 64 + m * 32 + r31;
        #pragma unroll
        for (int ks = 0; ks < 4; ++ks)
            aoff[m][ks] = r * 128 + (((ks * 2 + kb2) ^ (r & 7)) << 4);
    }
    #pragma unroll
    for (int n = 0; n < NFR; ++n) {
        int c = wc * (BN / 2) + n * 32 + r31;
        #pragma unroll
        for (int ks = 0; ks < 4; ++ks)
            boff[n][ks] = c * 128 + (((ks * 2 + kb2) ^ (c & 7)) << 4);
    }

    f32x16 acc[2][NFR] = {};

    const int nt = K >> 6;

    // prologue: stage tile 0 into buf 0
    #pragma unroll
    for (int q = 0; q < 4; ++q)   async16(gA[q], (char*)As[0] + ldstA[q]);
    #pragma unroll
    for (int q = 0; q < NST; ++q) async16(gB[q], (char*)Bs[0] + ldstB[q]);
    __syncthreads();

    int cur = 0;
    for (int tt = 0; tt < nt; ++tt) {
        if (tt + 1 < nt) {
            const size_t koff = (size_t)(tt + 1) * 128;   // 64 elems * 2 B
            #pragma unroll
            for (int q = 0; q < 4; ++q)
                async16(gA[q] + koff, (char*)As[cur ^ 1] + ldstA[q]);
            #pragma unroll
            for (int q = 0; q < NST; ++q)
                async16(gB[q] + koff, (char*)Bs[cur ^ 1] + ldstB[q]);
        }

        const char* aB = (const char*)As[cur];
        const char* bB = (const char*)Bs[cur];
        #pragma unroll
        for (int ks = 0; ks < 4; ++ks) {
            bf16x8 af[2], bfr[NFR];
            #pragma unroll
            for (int m = 0; m < 2; ++m)
                af[m] = *reinterpret_cast<const bf16x8*>(aB + aoff[m][ks]);
            #pragma unroll
            for (int n = 0; n < NFR; ++n)
                bfr[n] = *reinterpret_cast<const bf16x8*>(bB + boff[n][ks]);

            #pragma unroll
            for (int m = 0; m < 2; ++m)
                #pragma unroll
                for (int n = 0; n < NFR; ++n)
                    acc[m][n] = __builtin_amdgcn_mfma_f32_32x32x16_bf16(
                        af[m], bfr[n], acc[m][n], 0, 0, 0);
        }
        __syncthreads();
        cur ^= 1;
    }

    // epilogue: col=lane&31, row=(reg&3)+8*(reg>>2)+4*kb2
    #pragma unroll
    for (int n = 0; n < NFR; ++n) {
        const int col_g = col0 + wc * (BN / 2) + n * 32 + r31;
        const float bn = bias[col_g];
        #pragma unroll
        for (int m = 0; m < 2; ++m) {
            const int row_base = row0 + wr * 64 + m * 32 + 4 * kb2;
            #pragma unroll
            for (int reg = 0; reg < 16; ++reg) {
                const int rowIn = (reg & 3) + 8 * (reg >> 2);
                float v = acc[m][n][reg] + bn;
                if (relu) v = fmaxf(v, 0.f);
                C[(size_t)(row_base + rowIn) * ldc + col_g] = f2bf(v);
            }
        }
    }
}

// ---------------------------------------------------------------------------
// Kernel 4: final layer 256 -> 1 + sigmoid. One wave per row.
// ---------------------------------------------------------------------------
__global__ __launch_bounds__(256) void final_layer_kernel(
    const unsigned short* __restrict__ A,   // (B,256) bf16
    const float* __restrict__ T4,
    const float* __restrict__ tb4,
    float* __restrict__ out)
{
    const int t = threadIdx.x;
    const int lane = t & 63;
    const int wave = t >> 6;
    const int row = blockIdx.x * 4 + wave;

    ushort4 a4 = reinterpret_cast<const ushort4*>(A + (size_t)row * 256)[lane];
    float4 w = reinterpret_cast<const float4*>(T4)[lane];
    float s = bf2f(a4.x) * w.x + bf2f(a4.y) * w.y + bf2f(a4.z) * w.z + bf2f(a4.w) * w.w;
    #pragma unroll
    for (int off = 32; off > 0; off >>= 1) s += __shfl_down(s, off, 64);
    if (lane == 0) out[row] = 1.f / (1.f + expf(-(s + tb4[0])));
}

// ---------------------------------------------------------------------------
extern "C" void kernel_launch(void* const* d_in, const int* in_sizes, int n_in,
                              void* d_out, int out_size, void* d_ws, size_t ws_size,
                              hipStream_t stream)
{
    const float* dense = (const float*)d_in[0];
    const int*   cat   = (const int*)d_in[1];
    const float* table = (const float*)d_in[2];
    const float* W0 = (const float*)d_in[3];
    const float* b0 = (const float*)d_in[4];
    const float* W1 = (const float*)d_in[5];
    const float* b1 = (const float*)d_in[6];
    const float* W2 = (const float*)d_in[7];
    const float* b2 = (const float*)d_in[8];
    const float* T0 = (const float*)d_in[9];
    const float* tb0 = (const float*)d_in[10];
    const float* T1 = (const float*)d_in[11];
    const float* tb1 = (const float*)d_in[12];
    const float* T2 = (const float*)d_in[13];
    const float* tb2 = (const float*)d_in[14];
    const float* T3 = (const float*)d_in[15];
    const float* tb3 = (const float*)d_in[16];
    const float* T4 = (const float*)d_in[17];
    const float* tb4 = (const float*)d_in[18];
    float* out = (float*)d_out;

    // workspace layout (1 MB units)
    char* ws = (char*)d_ws;
    unsigned short* A0   = (unsigned short*)(ws);                          // 8192x512  bf16  8 MB
    unsigned short* act1 = (unsigned short*)(ws + (((size_t)8)  << 20));   // 8192x1024 bf16 16 MB
    unsigned short* act2 = (unsigned short*)(ws + (((size_t)24) << 20));   // 8192x1024 bf16 16 MB
    unsigned short* h1   = (unsigned short*)(ws + (((size_t)44) << 20));   // 8192x512  bf16  8 MB
    unsigned short* h2   = (unsigned short*)(ws + (((size_t)52) << 20));   // 8192x256  bf16  4 MB
    unsigned short* W1t  = (unsigned short*)(ws + (((size_t)56) << 20));   // 256x512
    unsigned short* W2t  = (unsigned short*)(ws + (((size_t)57) << 20));   // 128x256
    unsigned short* T0t  = (unsigned short*)(ws + (((size_t)58) << 20));   // 1024x512
    unsigned short* T1t  = (unsigned short*)(ws + (((size_t)60) << 20));   // 1024x1024
    unsigned short* T2t  = (unsigned short*)(ws + (((size_t)63) << 20));   // 512x1024
    unsigned short* T3t  = (unsigned short*)(ws + (((size_t)66) << 20));   // 256x512

    // fused weight transpose descriptors: {W, Wt, K, N, nkb(=Kpad/32), tile0}
    TransDescs td;
    td.d[0] = { W1, W1t,  512,  256, 16,    0 };   // 16*8  = 128 tiles
    td.d[1] = { W2, W2t,  256,  128,  8,  128 };   // 8*4   = 32
    td.d[2] = { T0, T0t,  506, 1024, 16,  160 };   // 16*32 = 512
    td.d[3] = { T1, T1t, 1024, 1024, 32,  672 };   // 32*32 = 1024
    td.d[4] = { T2, T2t, 1024,  512, 32, 1696 };   // 32*16 = 512
    td.d[5] = { T3, T3t,  512,  256, 16, 2208 };   // 16*8  = 128
    // prep: transposes (2336 blocks) + bottom layer 1 (1024 blocks)
    hipLaunchKernelGGL(prep_kernel, dim3(N_TRANS_TILES + BATCH / 8), dim3(256), 0, stream,
                       td, dense, W0, b0, h1);

    // bottom layer 2: (B,512)@(512,256) -> h2, relu  [BN=64: 256 blocks]
    hipLaunchKernelGGL((gemm_bf16_kernel<64>), dim3(BATCH / 128, 256 / 64), dim3(256), 0, stream,
                       h1, W1t, b1, h2, 512, 256, 1);

    // bottom layer 3: (B,256)@(256,128) -> A0[:,0:128] (ldc=512)  [BN=64: 128 blocks]
    hipLaunchKernelGGL((gemm_bf16_kernel<64>), dim3(BATCH / 128, 128 / 64), dim3(256), 0, stream,
                       h2, W2t, b2, A0, 256, 512, 1);

    // gather + interaction -> A0[:,128:506], zero pad
    hipLaunchKernelGGL(interact_kernel, dim3(BATCH), dim3(256), 0, stream,
                       cat, table, A0);

    // top MLP (bf16 MFMA)
    hipLaunchKernelGGL((gemm_bf16_kernel<128>), dim3(BATCH / 128, 1024 / 128), dim3(256), 0, stream,
                       A0, T0t, tb0, act1, 512, 1024, 1);
    hipLaunchKernelGGL((gemm_bf16_kernel<128>), dim3(BATCH / 128, 1024 / 128), dim3(256), 0, stream,
                       act1, T1t, tb1, act2, 1024, 1024, 1);
    hipLaunchKernelGGL((gemm_bf16_kernel<128>), dim3(BATCH / 128, 512 / 128), dim3(256), 0, stream,
                       act2, T2t, tb2, act1, 1024, 512, 1);
    hipLaunchKernelGGL((gemm_bf16_kernel<64>), dim3(BATCH / 128, 256 / 64), dim3(256), 0, stream,
                       act1, T3t, tb3, act2, 512, 256, 1);

    // final layer
    hipLaunchKernelGGL(final_layer_kernel, dim3(BATCH / 4), dim3(256), 0, stream,
                       act2, T4, tb4, out);
}